// Round 1
// baseline (1087.330 us; speedup 1.0000x reference)
//
#include <hip/hip_runtime.h>
#include <cfloat>
#include <math.h>

#define N_NODES 20000
#define N_EDGES 320000
#define TOT_E   (N_EDGES + N_NODES)   // 340000 (with self-loops)
#define IN_F    512
#define HID     256
#define HEADS   4
#define OUT_F   256
#define H1DIM   (HEADS * HID)         // 1024
#define NEG_SLOPE 0.2f

__device__ __forceinline__ float lrelu(float x) { return x >= 0.f ? x : NEG_SLOPE * x; }

// ---------------- CSR-by-dst build ----------------
__global__ void k_count(const int* __restrict__ ei, int* __restrict__ deg) {
  int e = blockIdx.x * 256 + threadIdx.x;
  if (e >= TOT_E) return;
  int dst = (e < N_EDGES) ? ei[N_EDGES + e] : (e - N_EDGES);  // row 1 of [2,E]
  atomicAdd(&deg[dst], 1);
}

__global__ void k_scan(const int* __restrict__ deg, int* __restrict__ off) {
  __shared__ int part[256];
  int tid = threadIdx.x;
  const int chunk = (N_NODES + 255) / 256;
  int s0 = tid * chunk;
  int s1 = s0 + chunk; if (s1 > N_NODES) s1 = N_NODES; if (s0 > N_NODES) s0 = N_NODES;
  int s = 0;
  for (int i = s0; i < s1; ++i) s += deg[i];
  part[tid] = s;
  __syncthreads();
  for (int d = 1; d < 256; d <<= 1) {
    int v = (tid >= d) ? part[tid - d] : 0;
    __syncthreads();
    part[tid] += v;
    __syncthreads();
  }
  int run = (tid == 0) ? 0 : part[tid - 1];
  for (int i = s0; i < s1; ++i) { off[i] = run; run += deg[i]; }
  if (tid == 255) off[N_NODES] = run;
}

__global__ void k_fill(const int* __restrict__ ei, const int* __restrict__ off,
                       int* __restrict__ cur, int* __restrict__ csr_src) {
  int e = blockIdx.x * 256 + threadIdx.x;
  if (e >= TOT_E) return;
  int src, dst;
  if (e < N_EDGES) { src = ei[e]; dst = ei[N_EDGES + e]; }
  else             { src = dst = e - N_EDGES; }
  int pos = atomicAdd(&cur[dst], 1);
  csr_src[off[dst] + pos] = src;
}

// ---------------- tiled fp32 GEMM: C[M,N] = A[M,K] @ B[K,N] ----------------
#define BM 64
#define BN 64
#define BK 16
__global__ void k_sgemm(const float* __restrict__ A, const float* __restrict__ B,
                        float* __restrict__ C, int M, int N, int K) {
  __shared__ float As[BK][BM + 1];
  __shared__ float Bs[BK][BN + 1];
  int tid = threadIdx.x;                 // 256
  int tr = tid >> 4, tc = tid & 15;      // 16x16 threads, 4x4 each
  int row0 = blockIdx.y * BM, col0 = blockIdx.x * BN;
  float acc[4][4] = {};
  for (int k0 = 0; k0 < K; k0 += BK) {
    for (int i = tid; i < BM * BK; i += 256) {
      int m = i >> 4, kk = i & 15;       // 16 consecutive floats per row
      int gr = row0 + m;
      As[kk][m] = (gr < M) ? A[(size_t)gr * K + k0 + kk] : 0.f;
    }
    for (int i = tid; i < BK * BN; i += 256) {
      int kk = i >> 6, n = i & 63;       // consecutive n -> coalesced
      Bs[kk][n] = B[(size_t)(k0 + kk) * N + col0 + n];
    }
    __syncthreads();
#pragma unroll
    for (int kk = 0; kk < BK; ++kk) {
      float a[4], b[4];
#pragma unroll
      for (int i = 0; i < 4; ++i) a[i] = As[kk][tr * 4 + i];
#pragma unroll
      for (int j = 0; j < 4; ++j) b[j] = Bs[kk][tc * 4 + j];
#pragma unroll
      for (int i = 0; i < 4; ++i)
#pragma unroll
        for (int j = 0; j < 4; ++j) acc[i][j] += a[i] * b[j];
    }
    __syncthreads();
  }
#pragma unroll
  for (int i = 0; i < 4; ++i) {
    int gr = row0 + tr * 4 + i;
    if (gr < M) {
#pragma unroll
      for (int j = 0; j < 4; ++j) C[(size_t)gr * N + col0 + tc * 4 + j] = acc[i][j];
    }
  }
}

// ---------------- attention dot products ----------------
// layer 1: a_s[n,h] = dot(h1[n, h*256 : h*256+256], att_src1[h]); 4 waves, one per head
__global__ void k_attn1(const float* __restrict__ h1, const float* __restrict__ att_s,
                        const float* __restrict__ att_d, float* __restrict__ as,
                        float* __restrict__ ad) {
  int n = blockIdx.x;
  int head = threadIdx.x >> 6, lane = threadIdx.x & 63;
  const float* hp = h1 + (size_t)n * H1DIM + head * HID;
  float ss = 0.f, sd = 0.f;
  for (int c = lane; c < HID; c += 64) {
    float v = hp[c];
    ss += v * att_s[head * HID + c];
    sd += v * att_d[head * HID + c];
  }
#pragma unroll
  for (int d = 32; d; d >>= 1) { ss += __shfl_down(ss, d); sd += __shfl_down(sd, d); }
  if (lane == 0) { as[n * HEADS + head] = ss; ad[n * HEADS + head] = sd; }
}

// layer 2: single head over 256 channels; one wave per node
__global__ void k_attn2(const float* __restrict__ h2, const float* __restrict__ att_s,
                        const float* __restrict__ att_d, float* __restrict__ as,
                        float* __restrict__ ad) {
  int n = blockIdx.x;
  int lane = threadIdx.x;  // 64
  const float* hp = h2 + (size_t)n * OUT_F;
  float ss = 0.f, sd = 0.f;
  for (int c = lane; c < OUT_F; c += 64) {
    float v = hp[c];
    ss += v * att_s[c];
    sd += v * att_d[c];
  }
#pragma unroll
  for (int d = 32; d; d >>= 1) { ss += __shfl_down(ss, d); sd += __shfl_down(sd, d); }
  if (lane == 0) { as[n] = ss; ad[n] = sd; }
}

// ---------------- per-dst softmax aggregation ----------------
// layer 1: block = 256 threads; thread t owns channel t of each of the 4 heads
__global__ void k_agg1(const int* __restrict__ off, const int* __restrict__ csr_src,
                       const float* __restrict__ h1, const float* __restrict__ as,
                       const float* __restrict__ ad, const float* __restrict__ b1,
                       float* __restrict__ helu) {
  int n = blockIdx.x;
  int t = threadIdx.x;
  int wave = t >> 6, lane = t & 63;
  int beg = off[n], end = off[n + 1];
  float4 adv = *(const float4*)&ad[n * 4];

  // pass 1: per-head max logit (strided over edges)
  float mx[4] = {-FLT_MAX, -FLT_MAX, -FLT_MAX, -FLT_MAX};
  for (int p = beg + t; p < end; p += 256) {
    int s = csr_src[p];
    float4 av = *(const float4*)&as[s * 4];
    mx[0] = fmaxf(mx[0], lrelu(av.x + adv.x));
    mx[1] = fmaxf(mx[1], lrelu(av.y + adv.y));
    mx[2] = fmaxf(mx[2], lrelu(av.z + adv.z));
    mx[3] = fmaxf(mx[3], lrelu(av.w + adv.w));
  }
  __shared__ float smax[4][4];  // [wave][head]
#pragma unroll
  for (int d = 32; d; d >>= 1) {
#pragma unroll
    for (int k = 0; k < 4; ++k) mx[k] = fmaxf(mx[k], __shfl_down(mx[k], d));
  }
  if (lane == 0) {
#pragma unroll
    for (int k = 0; k < 4; ++k) smax[wave][k] = mx[k];
  }
  __syncthreads();
  float m[4];
#pragma unroll
  for (int k = 0; k < 4; ++k)
    m[k] = fmaxf(fmaxf(smax[0][k], smax[1][k]), fmaxf(smax[2][k], smax[3][k]));

  // pass 2: every thread walks all edges; weights recomputed (broadcast loads)
  float acc[4] = {0.f, 0.f, 0.f, 0.f};
  float sume[4] = {0.f, 0.f, 0.f, 0.f};
  for (int p = beg; p < end; ++p) {
    int s = csr_src[p];
    float4 av = *(const float4*)&as[s * 4];
    float w0 = __expf(lrelu(av.x + adv.x) - m[0]);
    float w1 = __expf(lrelu(av.y + adv.y) - m[1]);
    float w2 = __expf(lrelu(av.z + adv.z) - m[2]);
    float w3 = __expf(lrelu(av.w + adv.w) - m[3]);
    sume[0] += w0; sume[1] += w1; sume[2] += w2; sume[3] += w3;
    const float* hs = h1 + (size_t)s * H1DIM;
    acc[0] += w0 * hs[t];
    acc[1] += w1 * hs[HID + t];
    acc[2] += w2 * hs[2 * HID + t];
    acc[3] += w3 * hs[3 * HID + t];
  }
#pragma unroll
  for (int k = 0; k < 4; ++k) {
    float v = acc[k] / (sume[k] + 1e-16f) + b1[k * HID + t];
    v = v > 0.f ? v : expm1f(v);  // ELU
    helu[(size_t)n * H1DIM + k * HID + t] = v;
  }
}

// layer 2: single head, 256 channels, writes final output (+b2, no activation)
__global__ void k_agg2(const int* __restrict__ off, const int* __restrict__ csr_src,
                       const float* __restrict__ h2, const float* __restrict__ as,
                       const float* __restrict__ ad, const float* __restrict__ b2,
                       float* __restrict__ out) {
  int n = blockIdx.x;
  int t = threadIdx.x;
  int wave = t >> 6, lane = t & 63;
  int beg = off[n], end = off[n + 1];
  float adv = ad[n];

  float mx = -FLT_MAX;
  for (int p = beg + t; p < end; p += 256) {
    int s = csr_src[p];
    mx = fmaxf(mx, lrelu(as[s] + adv));
  }
  __shared__ float smax[4];
#pragma unroll
  for (int d = 32; d; d >>= 1) mx = fmaxf(mx, __shfl_down(mx, d));
  if (lane == 0) smax[wave] = mx;
  __syncthreads();
  float m = fmaxf(fmaxf(smax[0], smax[1]), fmaxf(smax[2], smax[3]));

  float acc = 0.f, sume = 0.f;
  for (int p = beg; p < end; ++p) {
    int s = csr_src[p];
    float w = __expf(lrelu(as[s] + adv) - m);
    sume += w;
    acc += w * h2[(size_t)s * OUT_F + t];
  }
  out[(size_t)n * OUT_F + t] = acc / (sume + 1e-16f) + b2[t];
}

// ---------------- launch ----------------
extern "C" void kernel_launch(void* const* d_in, const int* in_sizes, int n_in,
                              void* d_out, int out_size, void* d_ws, size_t ws_size,
                              hipStream_t stream) {
  const float* x      = (const float*)d_in[0];
  const int*   ei     = (const int*)d_in[1];
  const float* W1     = (const float*)d_in[2];
  const float* att_s1 = (const float*)d_in[3];
  const float* att_d1 = (const float*)d_in[4];
  const float* b1     = (const float*)d_in[5];
  const float* W2     = (const float*)d_in[6];
  const float* att_s2 = (const float*)d_in[7];
  const float* att_d2 = (const float*)d_in[8];
  const float* b2     = (const float*)d_in[9];
  float* out = (float*)d_out;

  char* w = (char*)d_ws;
  auto alloc = [&](size_t bytes) {
    char* p = w;
    w += (bytes + 255) & ~(size_t)255;
    return p;
  };
  int*   deg  = (int*)alloc((size_t)N_NODES * 4);
  int*   off  = (int*)alloc((size_t)(N_NODES + 1) * 4);
  int*   cur  = (int*)alloc((size_t)N_NODES * 4);
  int*   csr  = (int*)alloc((size_t)TOT_E * 4);
  float* as1  = (float*)alloc((size_t)N_NODES * HEADS * 4);
  float* ad1  = (float*)alloc((size_t)N_NODES * HEADS * 4);
  float* as2  = (float*)alloc((size_t)N_NODES * 4);
  float* ad2  = (float*)alloc((size_t)N_NODES * 4);
  float* h1   = (float*)alloc((size_t)N_NODES * H1DIM * 4);
  float* helu = (float*)alloc((size_t)N_NODES * H1DIM * 4);
  float* h2   = (float*)alloc((size_t)N_NODES * OUT_F * 4);
  if ((size_t)(w - (char*)d_ws) > ws_size) return;  // insufficient workspace — fail visibly

  hipMemsetAsync(deg, 0, (size_t)N_NODES * 4, stream);
  hipMemsetAsync(cur, 0, (size_t)N_NODES * 4, stream);

  k_count<<<(TOT_E + 255) / 256, 256, 0, stream>>>(ei, deg);
  k_scan<<<1, 256, 0, stream>>>(deg, off);
  k_fill<<<(TOT_E + 255) / 256, 256, 0, stream>>>(ei, off, cur, csr);

  dim3 g1(H1DIM / BN, (N_NODES + BM - 1) / BM);
  k_sgemm<<<g1, 256, 0, stream>>>(x, W1, h1, N_NODES, H1DIM, IN_F);
  k_attn1<<<N_NODES, 256, 0, stream>>>(h1, att_s1, att_d1, as1, ad1);
  k_agg1<<<N_NODES, 256, 0, stream>>>(off, csr, h1, as1, ad1, b1, helu);

  dim3 g2(OUT_F / BN, (N_NODES + BM - 1) / BM);
  k_sgemm<<<g2, 256, 0, stream>>>(helu, W2, h2, N_NODES, OUT_F, H1DIM);
  k_attn2<<<N_NODES, 64, 0, stream>>>(h2, att_s2, att_d2, as2, ad2);
  k_agg2<<<N_NODES, 256, 0, stream>>>(off, csr, h2, as2, ad2, b2, out);
}

// Round 2
// 465.863 us; speedup vs baseline: 2.3340x; 2.3340x over previous
//
#include <hip/hip_runtime.h>
#include <hip/hip_bf16.h>
#include <cfloat>
#include <math.h>

#define N_NODES 20000
#define M_PAD   20096            // 157 * 128
#define N_EDGES 320000
#define TOT_E   (N_EDGES + N_NODES)
#define IN_F    512
#define HID     256
#define HEADS   4
#define OUT_F   256
#define H1DIM   (HEADS * HID)    // 1024
#define NEG_SLOPE 0.2f

typedef __attribute__((ext_vector_type(8))) __bf16 bf16x8;
typedef __attribute__((ext_vector_type(4))) __bf16 bf16x4;
typedef __attribute__((ext_vector_type(4))) float f32x4;

__device__ __forceinline__ float lrelu(float x) { return x >= 0.f ? x : NEG_SLOPE * x; }

// ---------------- CSR-by-dst build ----------------
__global__ void k_count(const int* __restrict__ ei, int* __restrict__ deg) {
  int e = blockIdx.x * 256 + threadIdx.x;
  if (e >= TOT_E) return;
  int dst = (e < N_EDGES) ? ei[N_EDGES + e] : (e - N_EDGES);
  atomicAdd(&deg[dst], 1);
}

__global__ void k_scan(const int* __restrict__ deg, int* __restrict__ off) {
  __shared__ int part[256];
  int tid = threadIdx.x;
  const int chunk = (N_NODES + 255) / 256;
  int s0 = tid * chunk;
  int s1 = s0 + chunk; if (s1 > N_NODES) s1 = N_NODES; if (s0 > N_NODES) s0 = N_NODES;
  int s = 0;
  for (int i = s0; i < s1; ++i) s += deg[i];
  part[tid] = s;
  __syncthreads();
  for (int d = 1; d < 256; d <<= 1) {
    int v = (tid >= d) ? part[tid - d] : 0;
    __syncthreads();
    part[tid] += v;
    __syncthreads();
  }
  int run = (tid == 0) ? 0 : part[tid - 1];
  for (int i = s0; i < s1; ++i) { off[i] = run; run += deg[i]; }
  if (tid == 255) off[N_NODES] = run;
}

__global__ void k_fill(const int* __restrict__ ei, const int* __restrict__ off,
                       int* __restrict__ cur, int* __restrict__ csr_src) {
  int e = blockIdx.x * 256 + threadIdx.x;
  if (e >= TOT_E) return;
  int src, dst;
  if (e < N_EDGES) { src = ei[e]; dst = ei[N_EDGES + e]; }
  else             { src = dst = e - N_EDGES; }
  int pos = atomicAdd(&cur[dst], 1);
  csr_src[off[dst] + pos] = src;
}

// ---------------- fp32 -> bf16 conversion (vectorized, 4/thread) ----------------
__global__ void k_f2b(const float* __restrict__ in, __bf16* __restrict__ out, int n4) {
  int i = blockIdx.x * 256 + threadIdx.x;
  if (i >= n4) return;
  float4 v = ((const float4*)in)[i];
  bf16x4 o = { (__bf16)v.x, (__bf16)v.y, (__bf16)v.z, (__bf16)v.w };
  ((bf16x4*)out)[i] = o;
}

// ---------------- fp32 [R][C] -> bf16 [C][R] transpose ----------------
__global__ void k_tr_f2b(const float* __restrict__ in, __bf16* __restrict__ out,
                         int R, int Cc) {
  __shared__ float tile[32][33];
  int c0 = blockIdx.x * 32, r0 = blockIdx.y * 32;
  int tx = threadIdx.x & 31, ty = threadIdx.x >> 5;   // 256 thr: ty 0..7
  for (int rr = ty; rr < 32; rr += 8)
    tile[rr][tx] = in[(size_t)(r0 + rr) * Cc + c0 + tx];
  __syncthreads();
  for (int rr = ty; rr < 32; rr += 8)
    out[(size_t)(c0 + rr) * R + r0 + tx] = (__bf16)tile[tx][rr];
}

// ---------------- MFMA bf16 GEMM: C[M,N] = A[M,K] @ Bt[N,K]^T ----------------
// 128x128 tile, BK=64, 4 waves (2x2), 4x4 16x16x32 fragments per wave.
// LDS linear [128 rows][8 chunks of 16B]; chunk index XOR-swizzled with (row&7)
// applied on the GLOBAL source (global_load_lds writes linearly, m104/m173).
__global__ __launch_bounds__(256) void k_gemm_bf16(
    const __bf16* __restrict__ A,    // [>=gridDim.y*128][K]
    const __bf16* __restrict__ Bt,   // [N][K]
    float* __restrict__ C,           // [M][N]
    int M, int N, int K)
{
  __shared__ char lds[32768];
  char* As = lds;            // [128][64] bf16
  char* Bs = lds + 16384;    // [128][64] bf16 (n-major)

  const int t = threadIdx.x;
  const int lane = t & 63;
  const int wid = t >> 6;
  const int wm = wid >> 1, wn = wid & 1;
  const int row0 = blockIdx.y * 128;
  const int col0 = blockIdx.x * 128;

  f32x4 acc[4][4];
#pragma unroll
  for (int i = 0; i < 4; ++i)
#pragma unroll
    for (int j = 0; j < 4; ++j) acc[i][j] = (f32x4){0.f, 0.f, 0.f, 0.f};

  for (int k0 = 0; k0 < K; k0 += 64) {
    // stage A tile
#pragma unroll
    for (int i = 0; i < 4; ++i) {
      int j = i * 256 + t;
      int r = j >> 3;
      int cc = (j & 7) ^ (r & 7);
      const __bf16* gp = A + (size_t)(row0 + r) * K + k0 + cc * 8;
      __builtin_amdgcn_global_load_lds(
          (const __attribute__((address_space(1))) void*)gp,
          (__attribute__((address_space(3))) void*)(As + j * 16), 16, 0, 0);
    }
    // stage Bt tile
#pragma unroll
    for (int i = 0; i < 4; ++i) {
      int j = i * 256 + t;
      int r = j >> 3;
      int cc = (j & 7) ^ (r & 7);
      const __bf16* gp = Bt + (size_t)(col0 + r) * K + k0 + cc * 8;
      __builtin_amdgcn_global_load_lds(
          (const __attribute__((address_space(1))) void*)gp,
          (__attribute__((address_space(3))) void*)(Bs + j * 16), 16, 0, 0);
    }
    __syncthreads();   // compiler drains vmcnt before barrier

#pragma unroll
    for (int ks = 0; ks < 2; ++ks) {
      bf16x8 af[4], bfr[4];
#pragma unroll
      for (int i = 0; i < 4; ++i) {
        int rA = wm * 64 + i * 16 + (lane & 15);
        int chA = (ks * 4 + (lane >> 4)) ^ (rA & 7);
        af[i] = *(const bf16x8*)(As + rA * 128 + chA * 16);
        int rB = wn * 64 + i * 16 + (lane & 15);
        int chB = (ks * 4 + (lane >> 4)) ^ (rB & 7);
        bfr[i] = *(const bf16x8*)(Bs + rB * 128 + chB * 16);
      }
#pragma unroll
      for (int i = 0; i < 4; ++i)
#pragma unroll
        for (int jn = 0; jn < 4; ++jn)
          acc[i][jn] = __builtin_amdgcn_mfma_f32_16x16x32_bf16(
              af[i], bfr[jn], acc[i][jn], 0, 0, 0);
    }
    __syncthreads();
  }

  // epilogue: D lane l, reg r -> row=(l>>4)*4+r, col=l&15 (m89/m91 layout)
#pragma unroll
  for (int i = 0; i < 4; ++i) {
    int growb = row0 + wm * 64 + i * 16 + (lane >> 4) * 4;
#pragma unroll
    for (int jn = 0; jn < 4; ++jn) {
      int gcol = col0 + wn * 64 + jn * 16 + (lane & 15);
#pragma unroll
      for (int r = 0; r < 4; ++r) {
        int grow = growb + r;
        if (grow < M) C[(size_t)grow * N + gcol] = acc[i][jn][r];
      }
    }
  }
}

// ---------------- attention dot products ----------------
__global__ void k_attn1(const float* __restrict__ h1, const float* __restrict__ att_s,
                        const float* __restrict__ att_d, float* __restrict__ as,
                        float* __restrict__ ad) {
  int n = blockIdx.x;
  int head = threadIdx.x >> 6, lane = threadIdx.x & 63;
  const float* hp = h1 + (size_t)n * H1DIM + head * HID;
  float ss = 0.f, sd = 0.f;
  for (int c = lane; c < HID; c += 64) {
    float v = hp[c];
    ss += v * att_s[head * HID + c];
    sd += v * att_d[head * HID + c];
  }
#pragma unroll
  for (int d = 32; d; d >>= 1) { ss += __shfl_down(ss, d); sd += __shfl_down(sd, d); }
  if (lane == 0) { as[n * HEADS + head] = ss; ad[n * HEADS + head] = sd; }
}

__global__ void k_attn2(const float* __restrict__ h2, const float* __restrict__ att_s,
                        const float* __restrict__ att_d, float* __restrict__ as,
                        float* __restrict__ ad) {
  int n = blockIdx.x;
  int lane = threadIdx.x;
  const float* hp = h2 + (size_t)n * OUT_F;
  float ss = 0.f, sd = 0.f;
  for (int c = lane; c < OUT_F; c += 64) {
    float v = hp[c];
    ss += v * att_s[c];
    sd += v * att_d[c];
  }
#pragma unroll
  for (int d = 32; d; d >>= 1) { ss += __shfl_down(ss, d); sd += __shfl_down(sd, d); }
  if (lane == 0) { as[n] = ss; ad[n] = sd; }
}

// ---------------- per-dst softmax aggregation ----------------
// layer 1: writes ELU output directly as bf16 (A operand of GEMM2)
__global__ void k_agg1(const int* __restrict__ off, const int* __restrict__ csr_src,
                       const float* __restrict__ h1, const float* __restrict__ as,
                       const float* __restrict__ ad, const float* __restrict__ b1,
                       __bf16* __restrict__ heluB) {
  int n = blockIdx.x;
  int t = threadIdx.x;
  int wave = t >> 6, lane = t & 63;
  int beg = off[n], end = off[n + 1];
  float4 adv = *(const float4*)&ad[n * 4];

  float mx[4] = {-FLT_MAX, -FLT_MAX, -FLT_MAX, -FLT_MAX};
  for (int p = beg + t; p < end; p += 256) {
    int s = csr_src[p];
    float4 av = *(const float4*)&as[s * 4];
    mx[0] = fmaxf(mx[0], lrelu(av.x + adv.x));
    mx[1] = fmaxf(mx[1], lrelu(av.y + adv.y));
    mx[2] = fmaxf(mx[2], lrelu(av.z + adv.z));
    mx[3] = fmaxf(mx[3], lrelu(av.w + adv.w));
  }
  __shared__ float smax[4][4];
#pragma unroll
  for (int d = 32; d; d >>= 1) {
#pragma unroll
    for (int k = 0; k < 4; ++k) mx[k] = fmaxf(mx[k], __shfl_down(mx[k], d));
  }
  if (lane == 0) {
#pragma unroll
    for (int k = 0; k < 4; ++k) smax[wave][k] = mx[k];
  }
  __syncthreads();
  float m[4];
#pragma unroll
  for (int k = 0; k < 4; ++k)
    m[k] = fmaxf(fmaxf(smax[0][k], smax[1][k]), fmaxf(smax[2][k], smax[3][k]));

  float acc[4] = {0.f, 0.f, 0.f, 0.f};
  float sume[4] = {0.f, 0.f, 0.f, 0.f};
  for (int p = beg; p < end; ++p) {
    int s = csr_src[p];
    float4 av = *(const float4*)&as[s * 4];
    float w0 = __expf(lrelu(av.x + adv.x) - m[0]);
    float w1 = __expf(lrelu(av.y + adv.y) - m[1]);
    float w2 = __expf(lrelu(av.z + adv.z) - m[2]);
    float w3 = __expf(lrelu(av.w + adv.w) - m[3]);
    sume[0] += w0; sume[1] += w1; sume[2] += w2; sume[3] += w3;
    const float* hs = h1 + (size_t)s * H1DIM;
    acc[0] += w0 * hs[t];
    acc[1] += w1 * hs[HID + t];
    acc[2] += w2 * hs[2 * HID + t];
    acc[3] += w3 * hs[3 * HID + t];
  }
#pragma unroll
  for (int k = 0; k < 4; ++k) {
    float v = acc[k] / (sume[k] + 1e-16f) + b1[k * HID + t];
    v = v > 0.f ? v : expm1f(v);  // ELU
    heluB[(size_t)n * H1DIM + k * HID + t] = (__bf16)v;
  }
}

__global__ void k_agg2(const int* __restrict__ off, const int* __restrict__ csr_src,
                       const float* __restrict__ h2, const float* __restrict__ as,
                       const float* __restrict__ ad, const float* __restrict__ b2,
                       float* __restrict__ out) {
  int n = blockIdx.x;
  int t = threadIdx.x;
  int wave = t >> 6, lane = t & 63;
  int beg = off[n], end = off[n + 1];
  float adv = ad[n];

  float mx = -FLT_MAX;
  for (int p = beg + t; p < end; p += 256) {
    int s = csr_src[p];
    mx = fmaxf(mx, lrelu(as[s] + adv));
  }
  __shared__ float smax[4];
#pragma unroll
  for (int d = 32; d; d >>= 1) mx = fmaxf(mx, __shfl_down(mx, d));
  if (lane == 0) smax[wave] = mx;
  __syncthreads();
  float m = fmaxf(fmaxf(smax[0], smax[1]), fmaxf(smax[2], smax[3]));

  float acc = 0.f, sume = 0.f;
  for (int p = beg; p < end; ++p) {
    int s = csr_src[p];
    float w = __expf(lrelu(as[s] + adv) - m);
    sume += w;
    acc += w * h2[(size_t)s * OUT_F + t];
  }
  out[(size_t)n * OUT_F + t] = acc / (sume + 1e-16f) + b2[t];
}

// ---------------- launch ----------------
extern "C" void kernel_launch(void* const* d_in, const int* in_sizes, int n_in,
                              void* d_out, int out_size, void* d_ws, size_t ws_size,
                              hipStream_t stream) {
  const float* x      = (const float*)d_in[0];
  const int*   ei     = (const int*)d_in[1];
  const float* W1     = (const float*)d_in[2];
  const float* att_s1 = (const float*)d_in[3];
  const float* att_d1 = (const float*)d_in[4];
  const float* b1     = (const float*)d_in[5];
  const float* W2     = (const float*)d_in[6];
  const float* att_s2 = (const float*)d_in[7];
  const float* att_d2 = (const float*)d_in[8];
  const float* b2     = (const float*)d_in[9];
  float* out = (float*)d_out;

  char* w = (char*)d_ws;
  auto alloc = [&](size_t bytes) {
    char* p = w;
    w += (bytes + 255) & ~(size_t)255;
    return p;
  };
  int*    deg   = (int*)alloc((size_t)N_NODES * 4);
  int*    off   = (int*)alloc((size_t)(N_NODES + 1) * 4);
  int*    cur   = (int*)alloc((size_t)N_NODES * 4);
  int*    csr   = (int*)alloc((size_t)TOT_E * 4);
  float*  as1   = (float*)alloc((size_t)N_NODES * HEADS * 4);
  float*  ad1   = (float*)alloc((size_t)N_NODES * HEADS * 4);
  float*  as2   = (float*)alloc((size_t)N_NODES * 4);
  float*  ad2   = (float*)alloc((size_t)N_NODES * 4);
  __bf16* xb    = (__bf16*)alloc((size_t)M_PAD * IN_F * 2);
  __bf16* w1t   = (__bf16*)alloc((size_t)H1DIM * IN_F * 2);
  __bf16* w2t   = (__bf16*)alloc((size_t)OUT_F * H1DIM * 2);
  float*  h1    = (float*)alloc((size_t)N_NODES * H1DIM * 4);
  __bf16* heluB = (__bf16*)alloc((size_t)M_PAD * H1DIM * 2);
  float*  h2    = (float*)alloc((size_t)N_NODES * OUT_F * 4);
  if ((size_t)(w - (char*)d_ws) > ws_size) return;

  hipMemsetAsync(deg, 0, (size_t)N_NODES * 4, stream);
  hipMemsetAsync(cur, 0, (size_t)N_NODES * 4, stream);

  k_count<<<(TOT_E + 255) / 256, 256, 0, stream>>>(ei, deg);
  k_scan<<<1, 256, 0, stream>>>(deg, off);
  k_fill<<<(TOT_E + 255) / 256, 256, 0, stream>>>(ei, off, cur, csr);

  // dtype prep
  int n4 = N_NODES * IN_F / 4;
  k_f2b<<<(n4 + 255) / 256, 256, 0, stream>>>(x, xb, n4);
  k_tr_f2b<<<dim3(H1DIM / 32, IN_F / 32), 256, 0, stream>>>(W1, w1t, IN_F, H1DIM);
  k_tr_f2b<<<dim3(OUT_F / 32, H1DIM / 32), 256, 0, stream>>>(W2, w2t, H1DIM, OUT_F);

  // layer 1
  k_gemm_bf16<<<dim3(H1DIM / 128, M_PAD / 128), 256, 0, stream>>>(
      xb, w1t, h1, N_NODES, H1DIM, IN_F);
  k_attn1<<<N_NODES, 256, 0, stream>>>(h1, att_s1, att_d1, as1, ad1);
  k_agg1<<<N_NODES, 256, 0, stream>>>(off, csr, h1, as1, ad1, b1, heluB);

  // layer 2
  k_gemm_bf16<<<dim3(OUT_F / 128, M_PAD / 128), 256, 0, stream>>>(
      heluB, w2t, h2, N_NODES, OUT_F, H1DIM);
  k_attn2<<<N_NODES, 64, 0, stream>>>(h2, att_s2, att_d2, as2, ad2);
  k_agg2<<<N_NODES, 256, 0, stream>>>(off, csr, h2, as2, ad2, b2, out);
}

// Round 3
// 299.492 us; speedup vs baseline: 3.6306x; 1.5555x over previous
//
#include <hip/hip_runtime.h>
#include <hip/hip_bf16.h>
#include <cfloat>
#include <math.h>

#define N_NODES 20000
#define M_PAD   20096            // 157 * 128
#define N_EDGES 320000
#define TOT_E   (N_EDGES + N_NODES)
#define IN_F    512
#define HID     256
#define HEADS   4
#define OUT_F   256
#define H1DIM   (HEADS * HID)    // 1024
#define NEG_SLOPE 0.2f

typedef __attribute__((ext_vector_type(8))) __bf16 bf16x8;
typedef __attribute__((ext_vector_type(4))) __bf16 bf16x4;
typedef __attribute__((ext_vector_type(4))) float f32x4;

__device__ __forceinline__ float lrelu(float x) { return x >= 0.f ? x : NEG_SLOPE * x; }

// ---------------- CSR-by-dst build ----------------
__global__ void k_count(const int* __restrict__ ei, int* __restrict__ deg) {
  int e = blockIdx.x * 256 + threadIdx.x;
  if (e >= TOT_E) return;
  int dst = (e < N_EDGES) ? ei[N_EDGES + e] : (e - N_EDGES);
  atomicAdd(&deg[dst], 1);
}

__global__ void k_scan(const int* __restrict__ deg, int* __restrict__ off) {
  __shared__ int part[256];
  int tid = threadIdx.x;
  const int chunk = (N_NODES + 255) / 256;
  int s0 = tid * chunk;
  int s1 = s0 + chunk; if (s1 > N_NODES) s1 = N_NODES; if (s0 > N_NODES) s0 = N_NODES;
  int s = 0;
  for (int i = s0; i < s1; ++i) s += deg[i];
  part[tid] = s;
  __syncthreads();
  for (int d = 1; d < 256; d <<= 1) {
    int v = (tid >= d) ? part[tid - d] : 0;
    __syncthreads();
    part[tid] += v;
    __syncthreads();
  }
  int run = (tid == 0) ? 0 : part[tid - 1];
  for (int i = s0; i < s1; ++i) { off[i] = run; run += deg[i]; }
  if (tid == 255) off[N_NODES] = run;
}

__global__ void k_fill(const int* __restrict__ ei, const int* __restrict__ off,
                       int* __restrict__ cur, int* __restrict__ csr_src) {
  int e = blockIdx.x * 256 + threadIdx.x;
  if (e >= TOT_E) return;
  int src, dst;
  if (e < N_EDGES) { src = ei[e]; dst = ei[N_EDGES + e]; }
  else             { src = dst = e - N_EDGES; }
  int pos = atomicAdd(&cur[dst], 1);
  csr_src[off[dst] + pos] = src;
}

// ---------------- fp32 -> bf16 conversion ----------------
__global__ void k_f2b(const float* __restrict__ in, __bf16* __restrict__ out, int n4) {
  int i = blockIdx.x * 256 + threadIdx.x;
  if (i >= n4) return;
  float4 v = ((const float4*)in)[i];
  bf16x4 o = { (__bf16)v.x, (__bf16)v.y, (__bf16)v.z, (__bf16)v.w };
  ((bf16x4*)out)[i] = o;
}

// ---------------- fp32 [R][C] -> bf16 [C][R] transpose ----------------
__global__ void k_tr_f2b(const float* __restrict__ in, __bf16* __restrict__ out,
                         int R, int Cc) {
  __shared__ float tile[32][33];
  int c0 = blockIdx.x * 32, r0 = blockIdx.y * 32;
  int tx = threadIdx.x & 31, ty = threadIdx.x >> 5;
  for (int rr = ty; rr < 32; rr += 8)
    tile[rr][tx] = in[(size_t)(r0 + rr) * Cc + c0 + tx];
  __syncthreads();
  for (int rr = ty; rr < 32; rr += 8)
    out[(size_t)(c0 + rr) * R + r0 + tx] = (__bf16)tile[tx][rr];
}

// ---------------- MFMA bf16 GEMM: Cb[M,N] = A[M,K] @ Bt[N,K]^T  (bf16 out) ----------------
__global__ __launch_bounds__(256) void k_gemm_bf16(
    const __bf16* __restrict__ A,    // [>=gridDim.y*128][K]
    const __bf16* __restrict__ Bt,   // [N][K]
    __bf16* __restrict__ Cb,         // [M][N] bf16
    int M, int N, int K)
{
  __shared__ char lds[32768];
  char* As = lds;            // [128][64] bf16
  char* Bs = lds + 16384;

  const int t = threadIdx.x;
  const int lane = t & 63;
  const int wid = t >> 6;
  const int wm = wid >> 1, wn = wid & 1;
  const int row0 = blockIdx.y * 128;
  const int col0 = blockIdx.x * 128;

  f32x4 acc[4][4];
#pragma unroll
  for (int i = 0; i < 4; ++i)
#pragma unroll
    for (int j = 0; j < 4; ++j) acc[i][j] = (f32x4){0.f, 0.f, 0.f, 0.f};

  for (int k0 = 0; k0 < K; k0 += 64) {
#pragma unroll
    for (int i = 0; i < 4; ++i) {
      int j = i * 256 + t;
      int r = j >> 3;
      int cc = (j & 7) ^ (r & 7);
      const __bf16* gp = A + (size_t)(row0 + r) * K + k0 + cc * 8;
      __builtin_amdgcn_global_load_lds(
          (const __attribute__((address_space(1))) void*)gp,
          (__attribute__((address_space(3))) void*)(As + j * 16), 16, 0, 0);
    }
#pragma unroll
    for (int i = 0; i < 4; ++i) {
      int j = i * 256 + t;
      int r = j >> 3;
      int cc = (j & 7) ^ (r & 7);
      const __bf16* gp = Bt + (size_t)(col0 + r) * K + k0 + cc * 8;
      __builtin_amdgcn_global_load_lds(
          (const __attribute__((address_space(1))) void*)gp,
          (__attribute__((address_space(3))) void*)(Bs + j * 16), 16, 0, 0);
    }
    __syncthreads();

#pragma unroll
    for (int ks = 0; ks < 2; ++ks) {
      bf16x8 af[4], bfr[4];
#pragma unroll
      for (int i = 0; i < 4; ++i) {
        int rA = wm * 64 + i * 16 + (lane & 15);
        int chA = (ks * 4 + (lane >> 4)) ^ (rA & 7);
        af[i] = *(const bf16x8*)(As + rA * 128 + chA * 16);
        int rB = wn * 64 + i * 16 + (lane & 15);
        int chB = (ks * 4 + (lane >> 4)) ^ (rB & 7);
        bfr[i] = *(const bf16x8*)(Bs + rB * 128 + chB * 16);
      }
#pragma unroll
      for (int i = 0; i < 4; ++i)
#pragma unroll
        for (int jn = 0; jn < 4; ++jn)
          acc[i][jn] = __builtin_amdgcn_mfma_f32_16x16x32_bf16(
              af[i], bfr[jn], acc[i][jn], 0, 0, 0);
    }
    __syncthreads();
  }

#pragma unroll
  for (int i = 0; i < 4; ++i) {
    int growb = row0 + wm * 64 + i * 16 + (lane >> 4) * 4;
#pragma unroll
    for (int jn = 0; jn < 4; ++jn) {
      int gcol = col0 + wn * 64 + jn * 16 + (lane & 15);
#pragma unroll
      for (int r = 0; r < 4; ++r) {
        int grow = growb + r;
        if (grow < M) Cb[(size_t)grow * N + gcol] = (__bf16)acc[i][jn][r];
      }
    }
  }
}

// ---------------- attention dot products (bf16 h) ----------------
// layer 1: 256 thr; thread t -> head t>>6, channels 4t..4t+3 (global idx = b1/att idx)
__global__ void k_attn1(const __bf16* __restrict__ h1b, const float* __restrict__ att_s,
                        const float* __restrict__ att_d, float* __restrict__ as,
                        float* __restrict__ ad) {
  int n = blockIdx.x;
  int t = threadIdx.x;
  int head = t >> 6, lane = t & 63;
  bf16x4 hv = *(const bf16x4*)(h1b + (size_t)n * H1DIM + t * 4);
  float4 sv = *(const float4*)(att_s + t * 4);
  float4 dv = *(const float4*)(att_d + t * 4);
  float h0 = (float)hv[0], h1 = (float)hv[1], h2 = (float)hv[2], h3 = (float)hv[3];
  float ss = h0 * sv.x + h1 * sv.y + h2 * sv.z + h3 * sv.w;
  float sd = h0 * dv.x + h1 * dv.y + h2 * dv.z + h3 * dv.w;
#pragma unroll
  for (int d = 32; d; d >>= 1) { ss += __shfl_xor(ss, d); sd += __shfl_xor(sd, d); }
  if (lane == 0) { as[n * HEADS + head] = ss; ad[n * HEADS + head] = sd; }
}

// layer 2: 64 thr; lane -> channels 4*lane..4*lane+3
__global__ void k_attn2(const __bf16* __restrict__ h2b, const float* __restrict__ att_s,
                        const float* __restrict__ att_d, float* __restrict__ as,
                        float* __restrict__ ad) {
  int n = blockIdx.x;
  int lane = threadIdx.x;
  bf16x4 hv = *(const bf16x4*)(h2b + (size_t)n * OUT_F + lane * 4);
  float4 sv = *(const float4*)(att_s + lane * 4);
  float4 dv = *(const float4*)(att_d + lane * 4);
  float h0 = (float)hv[0], h1 = (float)hv[1], h2 = (float)hv[2], h3 = (float)hv[3];
  float ss = h0 * sv.x + h1 * sv.y + h2 * sv.z + h3 * sv.w;
  float sd = h0 * dv.x + h1 * dv.y + h2 * dv.z + h3 * dv.w;
#pragma unroll
  for (int d = 32; d; d >>= 1) { ss += __shfl_xor(ss, d); sd += __shfl_xor(sd, d); }
  if (lane == 0) { as[n] = ss; ad[n] = sd; }
}

// ---------------- per-dst softmax aggregation ----------------
// layer 1: 256 thr/dst. Weights computed once per (edge,head) into LDS;
// FMA phase: thread t owns channels 4t..4t+3 (head = t>>6), bf16x4 loads.
__global__ void k_agg1(const int* __restrict__ off, const int* __restrict__ csr_src,
                       const __bf16* __restrict__ h1b, const float* __restrict__ as,
                       const float* __restrict__ ad, const float* __restrict__ b1,
                       __bf16* __restrict__ heluB) {
  int n = blockIdx.x;
  int t = threadIdx.x;
  int wave = t >> 6, lane = t & 63;
  int beg = off[n], end = off[n + 1];
  float4 advv = *(const float4*)&ad[n * 4];
  float adv[4] = {advv.x, advv.y, advv.z, advv.w};

  // pass 1: per-head max logit
  float mx[4] = {-FLT_MAX, -FLT_MAX, -FLT_MAX, -FLT_MAX};
  for (int p = beg + t; p < end; p += 256) {
    int s = csr_src[p];
    float4 av = *(const float4*)&as[s * 4];
    mx[0] = fmaxf(mx[0], lrelu(av.x + adv[0]));
    mx[1] = fmaxf(mx[1], lrelu(av.y + adv[1]));
    mx[2] = fmaxf(mx[2], lrelu(av.z + adv[2]));
    mx[3] = fmaxf(mx[3], lrelu(av.w + adv[3]));
  }
  __shared__ float smax[4][4];
#pragma unroll
  for (int d = 32; d; d >>= 1) {
#pragma unroll
    for (int k = 0; k < 4; ++k) mx[k] = fmaxf(mx[k], __shfl_xor(mx[k], d));
  }
  if (lane == 0) {
#pragma unroll
    for (int k = 0; k < 4; ++k) smax[wave][k] = mx[k];
  }
  __syncthreads();
  float m[4];
#pragma unroll
  for (int k = 0; k < 4; ++k)
    m[k] = fmaxf(fmaxf(smax[0][k], smax[1][k]), fmaxf(smax[2][k], smax[3][k]));

  // pass 2: chunked weights in LDS + vectorized FMA
  __shared__ float wl[64][4];
  __shared__ int sl[64];
  __shared__ float ssum[4][4];
  float acc[4] = {0.f, 0.f, 0.f, 0.f};
  float psum = 0.f;
  const int myh = t & 3;
  const int idx = t >> 2;
  for (int e0 = beg; e0 < end; e0 += 64) {
    int cnt = min(64, end - e0);
    if (idx < cnt) {
      int s = csr_src[e0 + idx];
      float w = __expf(lrelu(as[s * 4 + myh] + adv[myh]) - m[myh]);
      wl[idx][myh] = w;
      psum += w;
      if (myh == 0) sl[idx] = s;
    }
    __syncthreads();
    for (int e = 0; e < cnt; ++e) {
      float wv = wl[e][wave];
      int s = sl[e];
      bf16x4 hv = *(const bf16x4*)(h1b + (size_t)s * H1DIM + t * 4);
      acc[0] += wv * (float)hv[0];
      acc[1] += wv * (float)hv[1];
      acc[2] += wv * (float)hv[2];
      acc[3] += wv * (float)hv[3];
    }
    __syncthreads();
  }
  // reduce psum across threads with same (t&3): within wave (16 lanes), then cross-wave
#pragma unroll
  for (int d = 4; d <= 32; d <<= 1) psum += __shfl_xor(psum, d);
  if (lane < 4) ssum[wave][lane] = psum;
  __syncthreads();
  int h = t >> 6;
  float sume = ssum[0][h] + ssum[1][h] + ssum[2][h] + ssum[3][h];
  float inv = 1.f / (sume + 1e-16f);
  float4 bv = *(const float4*)(b1 + t * 4);
  float v0 = acc[0] * inv + bv.x;
  float v1 = acc[1] * inv + bv.y;
  float v2 = acc[2] * inv + bv.z;
  float v3 = acc[3] * inv + bv.w;
  v0 = v0 > 0.f ? v0 : expm1f(v0);
  v1 = v1 > 0.f ? v1 : expm1f(v1);
  v2 = v2 > 0.f ? v2 : expm1f(v2);
  v3 = v3 > 0.f ? v3 : expm1f(v3);
  bf16x4 o = { (__bf16)v0, (__bf16)v1, (__bf16)v2, (__bf16)v3 };
  *(bf16x4*)(heluB + (size_t)n * H1DIM + t * 4) = o;
}

// layer 2: 64 thr/dst (1 wave); lane owns channels 4*lane..4*lane+3
__global__ void k_agg2(const int* __restrict__ off, const int* __restrict__ csr_src,
                       const __bf16* __restrict__ h2b, const float* __restrict__ as,
                       const float* __restrict__ ad, const float* __restrict__ b2,
                       float* __restrict__ out) {
  int n = blockIdx.x;
  int lane = threadIdx.x;
  int beg = off[n], end = off[n + 1];
  float adv = ad[n];

  float mx = -FLT_MAX;
  for (int p = beg + lane; p < end; p += 64) {
    int s = csr_src[p];
    mx = fmaxf(mx, lrelu(as[s] + adv));
  }
#pragma unroll
  for (int d = 32; d; d >>= 1) mx = fmaxf(mx, __shfl_xor(mx, d));
  float m = mx;

  __shared__ float wl[64];
  __shared__ int sl[64];
  float acc[4] = {0.f, 0.f, 0.f, 0.f};
  float psum = 0.f;
  for (int e0 = beg; e0 < end; e0 += 64) {
    int cnt = min(64, end - e0);
    if (lane < cnt) {
      int s = csr_src[e0 + lane];
      float w = __expf(lrelu(as[s] + adv) - m);
      wl[lane] = w;
      sl[lane] = s;
      psum += w;
    }
    __syncthreads();
    for (int e = 0; e < cnt; ++e) {
      float wv = wl[e];
      int s = sl[e];
      bf16x4 hv = *(const bf16x4*)(h2b + (size_t)s * OUT_F + lane * 4);
      acc[0] += wv * (float)hv[0];
      acc[1] += wv * (float)hv[1];
      acc[2] += wv * (float)hv[2];
      acc[3] += wv * (float)hv[3];
    }
    __syncthreads();
  }
#pragma unroll
  for (int d = 32; d; d >>= 1) psum += __shfl_xor(psum, d);
  float inv = 1.f / (psum + 1e-16f);
  float4 bv = *(const float4*)(b2 + lane * 4);
  float4 o = { acc[0] * inv + bv.x, acc[1] * inv + bv.y,
               acc[2] * inv + bv.z, acc[3] * inv + bv.w };
  *(float4*)(out + (size_t)n * OUT_F + lane * 4) = o;
}

// ---------------- launch ----------------
extern "C" void kernel_launch(void* const* d_in, const int* in_sizes, int n_in,
                              void* d_out, int out_size, void* d_ws, size_t ws_size,
                              hipStream_t stream) {
  const float* x      = (const float*)d_in[0];
  const int*   ei     = (const int*)d_in[1];
  const float* W1     = (const float*)d_in[2];
  const float* att_s1 = (const float*)d_in[3];
  const float* att_d1 = (const float*)d_in[4];
  const float* b1     = (const float*)d_in[5];
  const float* W2     = (const float*)d_in[6];
  const float* att_s2 = (const float*)d_in[7];
  const float* att_d2 = (const float*)d_in[8];
  const float* b2     = (const float*)d_in[9];
  float* out = (float*)d_out;

  char* w = (char*)d_ws;
  auto alloc = [&](size_t bytes) {
    char* p = w;
    w += (bytes + 255) & ~(size_t)255;
    return p;
  };
  int*    deg   = (int*)alloc((size_t)N_NODES * 4);
  int*    off   = (int*)alloc((size_t)(N_NODES + 1) * 4);
  int*    cur   = (int*)alloc((size_t)N_NODES * 4);
  int*    csr   = (int*)alloc((size_t)TOT_E * 4);
  float*  as1   = (float*)alloc((size_t)N_NODES * HEADS * 4);
  float*  ad1   = (float*)alloc((size_t)N_NODES * HEADS * 4);
  float*  as2   = (float*)alloc((size_t)N_NODES * 4);
  float*  ad2   = (float*)alloc((size_t)N_NODES * 4);
  __bf16* xb    = (__bf16*)alloc((size_t)M_PAD * IN_F * 2);
  __bf16* w1t   = (__bf16*)alloc((size_t)H1DIM * IN_F * 2);
  __bf16* w2t   = (__bf16*)alloc((size_t)OUT_F * H1DIM * 2);
  __bf16* h1b   = (__bf16*)alloc((size_t)M_PAD * H1DIM * 2);
  __bf16* heluB = (__bf16*)alloc((size_t)M_PAD * H1DIM * 2);
  __bf16* h2b   = (__bf16*)alloc((size_t)M_PAD * OUT_F * 2);
  if ((size_t)(w - (char*)d_ws) > ws_size) return;

  hipMemsetAsync(deg, 0, (size_t)N_NODES * 4, stream);
  hipMemsetAsync(cur, 0, (size_t)N_NODES * 4, stream);

  k_count<<<(TOT_E + 255) / 256, 256, 0, stream>>>(ei, deg);
  k_scan<<<1, 256, 0, stream>>>(deg, off);
  k_fill<<<(TOT_E + 255) / 256, 256, 0, stream>>>(ei, off, cur, csr);

  int n4 = N_NODES * IN_F / 4;
  k_f2b<<<(n4 + 255) / 256, 256, 0, stream>>>(x, xb, n4);
  k_tr_f2b<<<dim3(H1DIM / 32, IN_F / 32), 256, 0, stream>>>(W1, w1t, IN_F, H1DIM);
  k_tr_f2b<<<dim3(OUT_F / 32, H1DIM / 32), 256, 0, stream>>>(W2, w2t, H1DIM, OUT_F);

  // layer 1
  k_gemm_bf16<<<dim3(H1DIM / 128, M_PAD / 128), 256, 0, stream>>>(
      xb, w1t, h1b, N_NODES, H1DIM, IN_F);
  k_attn1<<<N_NODES, 256, 0, stream>>>(h1b, att_s1, att_d1, as1, ad1);
  k_agg1<<<N_NODES, 256, 0, stream>>>(off, csr, h1b, as1, ad1, b1, heluB);

  // layer 2
  k_gemm_bf16<<<dim3(OUT_F / 128, M_PAD / 128), 256, 0, stream>>>(
      heluB, w2t, h2b, N_NODES, OUT_F, H1DIM);
  k_attn2<<<N_NODES, 64, 0, stream>>>(h2b, att_s2, att_d2, as2, ad2);
  k_agg2<<<N_NODES, 64, 0, stream>>>(off, csr, h2b, as2, ad2, b2, out);
}

// Round 4
// 297.328 us; speedup vs baseline: 3.6570x; 1.0073x over previous
//
#include <hip/hip_runtime.h>
#include <hip/hip_bf16.h>
#include <cfloat>
#include <math.h>

#define N_NODES 20000
#define M_PAD   20096            // 157 * 128
#define N_EDGES 320000
#define TOT_E   (N_EDGES + N_NODES)
#define IN_F    512
#define HID     256
#define HEADS   4
#define OUT_F   256
#define H1DIM   (HEADS * HID)    // 1024
#define NEG_SLOPE 0.2f

typedef __attribute__((ext_vector_type(8))) __bf16 bf16x8;
typedef __attribute__((ext_vector_type(4))) __bf16 bf16x4;
typedef __attribute__((ext_vector_type(4))) float f32x4;

__device__ __forceinline__ float lrelu(float x) { return x >= 0.f ? x : NEG_SLOPE * x; }

// ---------------- CSR-by-dst build ----------------
__global__ void k_count(const int* __restrict__ ei, int* __restrict__ deg) {
  int e = blockIdx.x * 256 + threadIdx.x;
  if (e >= TOT_E) return;
  int dst = (e < N_EDGES) ? ei[N_EDGES + e] : (e - N_EDGES);
  atomicAdd(&deg[dst], 1);
}

__global__ void k_scan(const int* __restrict__ deg, int* __restrict__ off) {
  __shared__ int part[256];
  int tid = threadIdx.x;
  const int chunk = (N_NODES + 255) / 256;
  int s0 = tid * chunk;
  int s1 = s0 + chunk; if (s1 > N_NODES) s1 = N_NODES; if (s0 > N_NODES) s0 = N_NODES;
  int s = 0;
  for (int i = s0; i < s1; ++i) s += deg[i];
  part[tid] = s;
  __syncthreads();
  for (int d = 1; d < 256; d <<= 1) {
    int v = (tid >= d) ? part[tid - d] : 0;
    __syncthreads();
    part[tid] += v;
    __syncthreads();
  }
  int run = (tid == 0) ? 0 : part[tid - 1];
  for (int i = s0; i < s1; ++i) { off[i] = run; run += deg[i]; }
  if (tid == 255) off[N_NODES] = run;
}

__global__ void k_fill(const int* __restrict__ ei, const int* __restrict__ off,
                       int* __restrict__ cur, int* __restrict__ csr_src) {
  int e = blockIdx.x * 256 + threadIdx.x;
  if (e >= TOT_E) return;
  int src, dst;
  if (e < N_EDGES) { src = ei[e]; dst = ei[N_EDGES + e]; }
  else             { src = dst = e - N_EDGES; }
  int pos = atomicAdd(&cur[dst], 1);
  csr_src[off[dst] + pos] = src;
}

// ---------------- fp32 -> bf16 conversion ----------------
__global__ void k_f2b(const float* __restrict__ in, __bf16* __restrict__ out, int n4) {
  int i = blockIdx.x * 256 + threadIdx.x;
  if (i >= n4) return;
  float4 v = ((const float4*)in)[i];
  bf16x4 o = { (__bf16)v.x, (__bf16)v.y, (__bf16)v.z, (__bf16)v.w };
  ((bf16x4*)out)[i] = o;
}

// ---------------- fp32 [R][C] -> bf16 [C][R] transpose ----------------
__global__ void k_tr_f2b(const float* __restrict__ in, __bf16* __restrict__ out,
                         int R, int Cc) {
  __shared__ float tile[32][33];
  int c0 = blockIdx.x * 32, r0 = blockIdx.y * 32;
  int tx = threadIdx.x & 31, ty = threadIdx.x >> 5;
  for (int rr = ty; rr < 32; rr += 8)
    tile[rr][tx] = in[(size_t)(r0 + rr) * Cc + c0 + tx];
  __syncthreads();
  for (int rr = ty; rr < 32; rr += 8)
    out[(size_t)(c0 + rr) * R + r0 + tx] = (__bf16)tile[tx][rr];
}

// ---------------- MFMA bf16 GEMM: Cb[M,N] = A[M,K] @ Bt[N,K]^T  (bf16 out) ----------------
__global__ __launch_bounds__(256) void k_gemm_bf16(
    const __bf16* __restrict__ A,
    const __bf16* __restrict__ Bt,
    __bf16* __restrict__ Cb,
    int M, int N, int K)
{
  __shared__ char lds[32768];
  char* As = lds;
  char* Bs = lds + 16384;

  const int t = threadIdx.x;
  const int lane = t & 63;
  const int wid = t >> 6;
  const int wm = wid >> 1, wn = wid & 1;
  const int row0 = blockIdx.y * 128;
  const int col0 = blockIdx.x * 128;

  f32x4 acc[4][4];
#pragma unroll
  for (int i = 0; i < 4; ++i)
#pragma unroll
    for (int j = 0; j < 4; ++j) acc[i][j] = (f32x4){0.f, 0.f, 0.f, 0.f};

  for (int k0 = 0; k0 < K; k0 += 64) {
#pragma unroll
    for (int i = 0; i < 4; ++i) {
      int j = i * 256 + t;
      int r = j >> 3;
      int cc = (j & 7) ^ (r & 7);
      const __bf16* gp = A + (size_t)(row0 + r) * K + k0 + cc * 8;
      __builtin_amdgcn_global_load_lds(
          (const __attribute__((address_space(1))) void*)gp,
          (__attribute__((address_space(3))) void*)(As + j * 16), 16, 0, 0);
    }
#pragma unroll
    for (int i = 0; i < 4; ++i) {
      int j = i * 256 + t;
      int r = j >> 3;
      int cc = (j & 7) ^ (r & 7);
      const __bf16* gp = Bt + (size_t)(col0 + r) * K + k0 + cc * 8;
      __builtin_amdgcn_global_load_lds(
          (const __attribute__((address_space(1))) void*)gp,
          (__attribute__((address_space(3))) void*)(Bs + j * 16), 16, 0, 0);
    }
    __syncthreads();

#pragma unroll
    for (int ks = 0; ks < 2; ++ks) {
      bf16x8 af[4], bfr[4];
#pragma unroll
      for (int i = 0; i < 4; ++i) {
        int rA = wm * 64 + i * 16 + (lane & 15);
        int chA = (ks * 4 + (lane >> 4)) ^ (rA & 7);
        af[i] = *(const bf16x8*)(As + rA * 128 + chA * 16);
        int rB = wn * 64 + i * 16 + (lane & 15);
        int chB = (ks * 4 + (lane >> 4)) ^ (rB & 7);
        bfr[i] = *(const bf16x8*)(Bs + rB * 128 + chB * 16);
      }
#pragma unroll
      for (int i = 0; i < 4; ++i)
#pragma unroll
        for (int jn = 0; jn < 4; ++jn)
          acc[i][jn] = __builtin_amdgcn_mfma_f32_16x16x32_bf16(
              af[i], bfr[jn], acc[i][jn], 0, 0, 0);
    }
    __syncthreads();
  }

#pragma unroll
  for (int i = 0; i < 4; ++i) {
    int growb = row0 + wm * 64 + i * 16 + (lane >> 4) * 4;
#pragma unroll
    for (int jn = 0; jn < 4; ++jn) {
      int gcol = col0 + wn * 64 + jn * 16 + (lane & 15);
#pragma unroll
      for (int r = 0; r < 4; ++r) {
        int grow = growb + r;
        if (grow < M) Cb[(size_t)grow * N + gcol] = (__bf16)acc[i][jn][r];
      }
    }
  }
}

// ---------------- attention dot products (bf16 h) ----------------
__global__ void k_attn1(const __bf16* __restrict__ h1b, const float* __restrict__ att_s,
                        const float* __restrict__ att_d, float* __restrict__ as,
                        float* __restrict__ ad) {
  int n = blockIdx.x;
  int t = threadIdx.x;
  int head = t >> 6, lane = t & 63;
  bf16x4 hv = *(const bf16x4*)(h1b + (size_t)n * H1DIM + t * 4);
  float4 sv = *(const float4*)(att_s + t * 4);
  float4 dv = *(const float4*)(att_d + t * 4);
  float h0 = (float)hv[0], h1 = (float)hv[1], h2 = (float)hv[2], h3 = (float)hv[3];
  float ss = h0 * sv.x + h1 * sv.y + h2 * sv.z + h3 * sv.w;
  float sd = h0 * dv.x + h1 * dv.y + h2 * dv.z + h3 * dv.w;
#pragma unroll
  for (int d = 32; d; d >>= 1) { ss += __shfl_xor(ss, d); sd += __shfl_xor(sd, d); }
  if (lane == 0) { as[n * HEADS + head] = ss; ad[n * HEADS + head] = sd; }
}

__global__ void k_attn2(const __bf16* __restrict__ h2b, const float* __restrict__ att_s,
                        const float* __restrict__ att_d, float* __restrict__ as,
                        float* __restrict__ ad) {
  int n = blockIdx.x;
  int lane = threadIdx.x;
  bf16x4 hv = *(const bf16x4*)(h2b + (size_t)n * OUT_F + lane * 4);
  float4 sv = *(const float4*)(att_s + lane * 4);
  float4 dv = *(const float4*)(att_d + lane * 4);
  float h0 = (float)hv[0], h1 = (float)hv[1], h2 = (float)hv[2], h3 = (float)hv[3];
  float ss = h0 * sv.x + h1 * sv.y + h2 * sv.z + h3 * sv.w;
  float sd = h0 * dv.x + h1 * dv.y + h2 * dv.z + h3 * dv.w;
#pragma unroll
  for (int d = 32; d; d >>= 1) { ss += __shfl_xor(ss, d); sd += __shfl_xor(sd, d); }
  if (lane == 0) { as[n] = ss; ad[n] = sd; }
}

// ---------------- per-dst softmax aggregation (no-max exp: logits bounded) ----------------
// layer 1: 128 thr/dst. Thread t owns 8 channels t*8..t*8+7 (head = t>>5).
__global__ __launch_bounds__(128) void k_agg1(
    const int* __restrict__ off, const int* __restrict__ csr_src,
    const __bf16* __restrict__ h1b, const float* __restrict__ as,
    const float* __restrict__ ad, const float* __restrict__ b1,
    __bf16* __restrict__ heluB) {
  int n = blockIdx.x;
  int t = threadIdx.x;            // 0..127
  int wave = t >> 6, lane = t & 63;
  int beg = off[n], end = off[n + 1];
  float4 advv = *(const float4*)&ad[n * 4];
  float adv[4] = {advv.x, advv.y, advv.z, advv.w};

  __shared__ float wl[64][4];
  __shared__ int sl[64];
  __shared__ float ssumW[2][4];

  const int head = t >> 5;        // FMA-phase head (0..3)
  const int myh = t & 3;          // weight-phase head
  const int idx = t >> 2;         // weight-phase edge slot (0..31)

  float acc[8] = {0.f, 0.f, 0.f, 0.f, 0.f, 0.f, 0.f, 0.f};
  float psum = 0.f;               // belongs to head myh

  for (int e0 = beg; e0 < end; e0 += 64) {
    int cnt = min(64, end - e0);
    // weights: slots idx and idx+32, head myh
    if (idx < cnt) {
      int s = csr_src[e0 + idx];
      float w = __expf(lrelu(as[s * 4 + myh] + adv[myh]));
      wl[idx][myh] = w;
      psum += w;
      if (myh == 0) sl[idx] = s;
    }
    if (idx + 32 < cnt) {
      int s = csr_src[e0 + idx + 32];
      float w = __expf(lrelu(as[s * 4 + myh] + adv[myh]));
      wl[idx + 32][myh] = w;
      psum += w;
      if (myh == 0) sl[idx + 32] = s;
    }
    __syncthreads();
#pragma unroll 4
    for (int e = 0; e < cnt; ++e) {
      float wv = wl[e][head];
      int s = sl[e];
      bf16x8 hv = *(const bf16x8*)(h1b + (size_t)s * H1DIM + t * 8);
#pragma unroll
      for (int k = 0; k < 8; ++k) acc[k] += wv * (float)hv[k];
    }
    __syncthreads();
  }

  // reduce psum over lanes with equal (lane&3) within wave, then across 2 waves
#pragma unroll
  for (int d = 4; d <= 32; d <<= 1) psum += __shfl_xor(psum, d);
  if (lane < 4) ssumW[wave][lane] = psum;
  __syncthreads();
  float sume = ssumW[0][head] + ssumW[1][head];
  float inv = 1.f / (sume + 1e-16f);

  float4 bv0 = *(const float4*)(b1 + t * 8);
  float4 bv1 = *(const float4*)(b1 + t * 8 + 4);
  float bb[8] = {bv0.x, bv0.y, bv0.z, bv0.w, bv1.x, bv1.y, bv1.z, bv1.w};
  bf16x8 o;
#pragma unroll
  for (int k = 0; k < 8; ++k) {
    float v = acc[k] * inv + bb[k];
    v = v > 0.f ? v : expm1f(v);  // ELU
    o[k] = (__bf16)v;
  }
  *(bf16x8*)(heluB + (size_t)n * H1DIM + t * 8) = o;
}

// layer 2: 64 thr/dst; lane owns channels 4*lane..4*lane+3
__global__ void k_agg2(const int* __restrict__ off, const int* __restrict__ csr_src,
                       const __bf16* __restrict__ h2b, const float* __restrict__ as,
                       const float* __restrict__ ad, const float* __restrict__ b2,
                       float* __restrict__ out) {
  int n = blockIdx.x;
  int lane = threadIdx.x;
  int beg = off[n], end = off[n + 1];
  float adv = ad[n];

  __shared__ float wl[64];
  __shared__ int sl[64];
  float acc[4] = {0.f, 0.f, 0.f, 0.f};
  float psum = 0.f;
  for (int e0 = beg; e0 < end; e0 += 64) {
    int cnt = min(64, end - e0);
    if (lane < cnt) {
      int s = csr_src[e0 + lane];
      float w = __expf(lrelu(as[s] + adv));
      wl[lane] = w;
      sl[lane] = s;
      psum += w;
    }
    __syncthreads();
#pragma unroll 4
    for (int e = 0; e < cnt; ++e) {
      float wv = wl[e];
      int s = sl[e];
      bf16x4 hv = *(const bf16x4*)(h2b + (size_t)s * OUT_F + lane * 4);
      acc[0] += wv * (float)hv[0];
      acc[1] += wv * (float)hv[1];
      acc[2] += wv * (float)hv[2];
      acc[3] += wv * (float)hv[3];
    }
    __syncthreads();
  }
#pragma unroll
  for (int d = 32; d; d >>= 1) psum += __shfl_xor(psum, d);
  float inv = 1.f / (psum + 1e-16f);
  float4 bv = *(const float4*)(b2 + lane * 4);
  float4 o = { acc[0] * inv + bv.x, acc[1] * inv + bv.y,
               acc[2] * inv + bv.z, acc[3] * inv + bv.w };
  *(float4*)(out + (size_t)n * OUT_F + lane * 4) = o;
}

// ---------------- launch ----------------
extern "C" void kernel_launch(void* const* d_in, const int* in_sizes, int n_in,
                              void* d_out, int out_size, void* d_ws, size_t ws_size,
                              hipStream_t stream) {
  const float* x      = (const float*)d_in[0];
  const int*   ei     = (const int*)d_in[1];
  const float* W1     = (const float*)d_in[2];
  const float* att_s1 = (const float*)d_in[3];
  const float* att_d1 = (const float*)d_in[4];
  const float* b1     = (const float*)d_in[5];
  const float* W2     = (const float*)d_in[6];
  const float* att_s2 = (const float*)d_in[7];
  const float* att_d2 = (const float*)d_in[8];
  const float* b2     = (const float*)d_in[9];
  float* out = (float*)d_out;

  char* w = (char*)d_ws;
  auto alloc = [&](size_t bytes) {
    char* p = w;
    w += (bytes + 255) & ~(size_t)255;
    return p;
  };
  int*    deg   = (int*)alloc((size_t)N_NODES * 4);
  int*    off   = (int*)alloc((size_t)(N_NODES + 1) * 4);
  int*    cur   = (int*)alloc((size_t)N_NODES * 4);
  int*    csr   = (int*)alloc((size_t)TOT_E * 4);
  float*  as1   = (float*)alloc((size_t)N_NODES * HEADS * 4);
  float*  ad1   = (float*)alloc((size_t)N_NODES * HEADS * 4);
  float*  as2   = (float*)alloc((size_t)N_NODES * 4);
  float*  ad2   = (float*)alloc((size_t)N_NODES * 4);
  __bf16* xb    = (__bf16*)alloc((size_t)M_PAD * IN_F * 2);
  __bf16* w1t   = (__bf16*)alloc((size_t)H1DIM * IN_F * 2);
  __bf16* w2t   = (__bf16*)alloc((size_t)OUT_F * H1DIM * 2);
  __bf16* h1b   = (__bf16*)alloc((size_t)M_PAD * H1DIM * 2);
  __bf16* heluB = (__bf16*)alloc((size_t)M_PAD * H1DIM * 2);
  __bf16* h2b   = (__bf16*)alloc((size_t)M_PAD * OUT_F * 2);
  if ((size_t)(w - (char*)d_ws) > ws_size) return;

  hipMemsetAsync(deg, 0, (size_t)N_NODES * 4, stream);
  hipMemsetAsync(cur, 0, (size_t)N_NODES * 4, stream);

  k_count<<<(TOT_E + 255) / 256, 256, 0, stream>>>(ei, deg);
  k_scan<<<1, 256, 0, stream>>>(deg, off);
  k_fill<<<(TOT_E + 255) / 256, 256, 0, stream>>>(ei, off, cur, csr);

  int n4 = N_NODES * IN_F / 4;
  k_f2b<<<(n4 + 255) / 256, 256, 0, stream>>>(x, xb, n4);
  k_tr_f2b<<<dim3(H1DIM / 32, IN_F / 32), 256, 0, stream>>>(W1, w1t, IN_F, H1DIM);
  k_tr_f2b<<<dim3(OUT_F / 32, H1DIM / 32), 256, 0, stream>>>(W2, w2t, H1DIM, OUT_F);

  // layer 1
  k_gemm_bf16<<<dim3(H1DIM / 128, M_PAD / 128), 256, 0, stream>>>(
      xb, w1t, h1b, N_NODES, H1DIM, IN_F);
  k_attn1<<<N_NODES, 256, 0, stream>>>(h1b, att_s1, att_d1, as1, ad1);
  k_agg1<<<N_NODES, 128, 0, stream>>>(off, csr, h1b, as1, ad1, b1, heluB);

  // layer 2
  k_gemm_bf16<<<dim3(OUT_F / 128, M_PAD / 128), 256, 0, stream>>>(
      heluB, w2t, h2b, N_NODES, OUT_F, H1DIM);
  k_attn2<<<N_NODES, 64, 0, stream>>>(h2b, att_s2, att_d2, as2, ad2);
  k_agg2<<<N_NODES, 64, 0, stream>>>(off, csr, h2b, as2, ad2, b2, out);
}